// Round 4
// baseline (333.773 us; speedup 1.0000x reference)
//
#include <hip/hip_runtime.h>

// Problem constants
#define BB 4
#define TT 2048
#define CC 1024
#define C3 3072
#define HH 16
#define HD 64
#define BT 8192   // BB*TT

typedef __bf16 bf16x8 __attribute__((ext_vector_type(8)));
typedef float floatx4 __attribute__((ext_vector_type(4)));
typedef unsigned short u16;

__device__ __forceinline__ u16 f2bf(float f) {
  union { float f; unsigned u; } a; a.f = f;
  return (u16)((a.u + 0x7fffu + ((a.u >> 16) & 1u)) >> 16);  // RNE
}
__device__ __forceinline__ bf16x8 ld8(const u16* p) { return *(const bf16x8*)p; }
__device__ __forceinline__ floatx4 mfma16(bf16x8 a, bf16x8 b, floatx4 c) {
  return __builtin_amdgcn_mfma_f32_16x16x32_bf16(a, b, c, 0, 0, 0);
}
// Async global->LDS, 16B per lane. LDS dest is wave-uniform base + lane*16.
__device__ __forceinline__ void async_copy16(const u16* g, u16* l) {
  __builtin_amdgcn_global_load_lds(
      (const __attribute__((address_space(1))) unsigned int*)g,
      (__attribute__((address_space(3))) unsigned int*)(unsigned int)(unsigned long long)l,
      16, 0, 0);
}

// ---------------------------------------------------------------------------
// fp32 -> bf16 elementwise (for x)
// ---------------------------------------------------------------------------
__global__ __launch_bounds__(256) void tobf16_kernel(const float4* __restrict__ src,
                                                     ushort4* __restrict__ dst, int n4) {
  int i = blockIdx.x * 256 + threadIdx.x;
  if (i >= n4) return;
  float4 v = src[i];
  ushort4 o; o.x = f2bf(v.x); o.y = f2bf(v.y); o.z = f2bf(v.z); o.w = f2bf(v.w);
  dst[i] = o;
}

// ---------------------------------------------------------------------------
// fp32 [K][N] -> bf16 [N][K] transpose (LDS-tiled, 64x64 tiles)
// ---------------------------------------------------------------------------
__global__ __launch_bounds__(256) void transpose_bf16_kernel(const float* __restrict__ src,
                                                             u16* __restrict__ dst,
                                                             int K, int N) {
  __shared__ float s[64][65];
  const int t = threadIdx.x;
  const int r = t >> 4;           // 0..15
  const int c = (t & 15) * 4;     // 0..60
  const int k0 = blockIdx.y * 64, n0 = blockIdx.x * 64;
#pragma unroll
  for (int i = 0; i < 4; ++i) {
    float4 v = *(const float4*)&src[(size_t)(k0 + r + i * 16) * N + n0 + c];
    s[r + i * 16][c + 0] = v.x; s[r + i * 16][c + 1] = v.y;
    s[r + i * 16][c + 2] = v.z; s[r + i * 16][c + 3] = v.w;
  }
  __syncthreads();
#pragma unroll
  for (int i = 0; i < 4; ++i) {
    const int nn = r + i * 16;
    ushort4 o;
    o.x = f2bf(s[c + 0][nn]); o.y = f2bf(s[c + 1][nn]);
    o.z = f2bf(s[c + 2][nn]); o.w = f2bf(s[c + 3][nn]);
    *(ushort4*)&dst[(size_t)(n0 + nn) * K + k0 + c] = o;
  }
}

// ---------------------------------------------------------------------------
// GEMM (m97 structure): C[M,N] = A[M,K] @ B^T[N,K], 128x128 tile, BK=32.
// MODE 1: qkv epilogue via LDS bounce -> coalesced 128B stores
// MODE 2: fp32 out + bias, direct stores
// ---------------------------------------------------------------------------
template<int MODE>
__global__ __launch_bounds__(256) void gemm_kernel(
    const u16* __restrict__ A, const u16* __restrict__ B,
    const float* __restrict__ bias, float* __restrict__ outf,
    u16* __restrict__ qk, u16* __restrict__ vT,
    int M, int N, int K) {
  __shared__ u16 sA[128 * 32];
  __shared__ u16 sB[128 * 32];
  __shared__ u16 sT[(MODE == 1) ? (4 * 32 * 72) : 4];  // per-wave epilogue bounce

  const int t = threadIdx.x;
  const int w = t >> 6, lane = t & 63, lr = lane & 15, qd = lane >> 4;
  const int wm = w >> 1, wn = w & 1;
  const int m0 = blockIdx.y * 128, n0 = blockIdx.x * 128;

  const int sr = t >> 2;          // staging row 0..63
  const int sc = (t & 3) * 8;     // staging col (u16 units)
  const u16* Ag = A + (size_t)(m0 + sr) * K + sc;
  const u16* Bg = B + (size_t)(n0 + sr) * K + sc;
  u16* sAw = sA + w * 512;
  u16* sBw = sB + w * 512;

  floatx4 acc[4][4] = {};

  for (int k0 = 0; k0 < K; k0 += 32) {
    async_copy16(Ag + k0, sAw);
    async_copy16(Ag + (size_t)64 * K + k0, sAw + 2048);
    async_copy16(Bg + k0, sBw);
    async_copy16(Bg + (size_t)64 * K + k0, sBw + 2048);
    __syncthreads();

    bf16x8 af[4], bf[4];
#pragma unroll
    for (int mj = 0; mj < 4; ++mj) af[mj] = ld8(&sA[(wm * 64 + mj * 16 + lr) * 32 + qd * 8]);
#pragma unroll
    for (int nj = 0; nj < 4; ++nj) bf[nj] = ld8(&sB[(wn * 64 + nj * 16 + lr) * 32 + qd * 8]);
#pragma unroll
    for (int mj = 0; mj < 4; ++mj)
#pragma unroll
      for (int nj = 0; nj < 4; ++nj)
        acc[mj][nj] = mfma16(af[mj], bf[nj], acc[mj][nj]);
    __syncthreads();
  }

  // Epilogue. D layout: col(N)=lane&15, row(M)=(lane>>4)*4+i  [m89/m91]
  const int rowg0 = m0 + wm * 64;
  const int colg0 = n0 + wn * 64;
  if constexpr (MODE == 2) {
#pragma unroll
    for (int nj = 0; nj < 4; ++nj) {
      const int col = colg0 + nj * 16 + lr;
      const float bv = bias[col];
#pragma unroll
      for (int mj = 0; mj < 4; ++mj)
#pragma unroll
        for (int i = 0; i < 4; ++i)
          outf[(size_t)(rowg0 + mj * 16 + qd * 4 + i) * N + col] = acc[mj][nj][i] + bv;
    }
  } else {
    u16* Tw = sT + w * (32 * 72);
    const bool isV = (n0 >= 2 * CC);   // block-uniform
    if (!isV) {
      // Q/K: row-major bounce, then 128B-coalesced row stores
#pragma unroll
      for (int half = 0; half < 2; ++half) {
#pragma unroll
        for (int m2 = 0; m2 < 2; ++m2)
#pragma unroll
          for (int nj = 0; nj < 4; ++nj)
#pragma unroll
            for (int i = 0; i < 4; ++i)
              Tw[(m2 * 16 + qd * 4 + i) * 72 + nj * 16 + lr] =
                  f2bf(acc[half * 2 + m2][nj][i]);
#pragma unroll
        for (int s = 0; s < 4; ++s) {
          const int rl = s * 8 + (lane >> 3);
          const int c0 = (lane & 7) * 8;
          *(bf16x8*)&qk[(size_t)(rowg0 + half * 32 + rl) * (2 * CC) + colg0 + c0] =
              ld8(&Tw[rl * 72 + c0]);
        }
      }
    } else {
      // V: transpose bounce -> vT[b*1024 + dim][t], 128B-coalesced
      const int bI = m0 >> 11;
      const int tbase = (m0 & (TT - 1)) + wm * 64;
      const int dim0 = colg0 - 2 * CC;
#pragma unroll
      for (int half = 0; half < 2; ++half) {
#pragma unroll
        for (int n2 = 0; n2 < 2; ++n2)
#pragma unroll
          for (int mj = 0; mj < 4; ++mj)
#pragma unroll
            for (int i = 0; i < 4; ++i)
              Tw[(n2 * 16 + lr) * 72 + mj * 16 + qd * 4 + i] =
                  f2bf(acc[mj][half * 2 + n2][i]);
#pragma unroll
        for (int s = 0; s < 4; ++s) {
          const int dl = s * 8 + (lane >> 3);
          const int t0 = (lane & 7) * 8;
          *(bf16x8*)&vT[((size_t)(bI << 10) + dim0 + half * 32 + dl) * TT + tbase + t0] =
              ld8(&Tw[dl * 72 + t0]);
        }
      }
    }
  }
}

// ---------------------------------------------------------------------------
// Causal flash attention, fixed-max softmax. Block = 128 q-rows (4 waves x
// 2 q-frags); K/V frags loaded once per 64-key tile into VGPRs and reused
// across both q-frags (halves LDS-pipe cost vs 1 frag/wave).
// S^T via mfma(A=K,B=Q); P pack -> per-wave LDS -> A-operand; PV -> C-layout.
// qtile = 15-blockIdx.x: longest blocks first (LPT).
// ---------------------------------------------------------------------------
__global__ __launch_bounds__(256, 3) void attn_kernel(const u16* __restrict__ qk,
                                                      const u16* __restrict__ vT,
                                                      u16* __restrict__ att) {
  __shared__ u16 sK0[64 * 32], sK1[64 * 32];   // K dims 0..31 / 32..63
  __shared__ u16 sV0[64 * 32], sV1[64 * 32];   // V^T keys 0..31 / 32..63
  __shared__ u16 sP[4 * 16 * 72];              // per-wave P [q=16][key=64], stride 72

  const int t = threadIdx.x;
  const int w = t >> 6, lane = t & 63, lr = lane & 15, qd = lane >> 4;
  const int qtile = 15 - blockIdx.x;
  const int bh = blockIdx.y;
  const int b = bh >> 4, h = bh & 15;
  const int q0 = qtile * 128;
  const u16* qbase = qk + (size_t)b * TT * (2 * CC);

  // Q frags (B-operand): frag f covers q = q0 + w*32 + f*16 + lr
  bf16x8 qf[2][2];
#pragma unroll
  for (int f = 0; f < 2; ++f) {
    const u16* qp = qbase + (size_t)(q0 + w * 32 + f * 16 + lr) * (2 * CC) + h * HD;
    qf[f][0] = ld8(qp + qd * 8);
    qf[f][1] = ld8(qp + 32 + qd * 8);
  }

  const int sr = t >> 2, sc = (t & 3) * 8;
  const u16* Kg = qbase + (size_t)sr * (2 * CC) + CC + h * HD + sc;
  const u16* Vg = vT + ((size_t)bh * HD + sr) * TT + sc;
  u16* sK0w = sK0 + w * 512; u16* sK1w = sK1 + w * 512;
  u16* sV0w = sV0 + w * 512; u16* sV1w = sV1 + w * 512;

  float lsum[2] = {0.f, 0.f};       // per-lane partial, q = lr (per frag)
  floatx4 o[2][4] = {};
  const float SC = 0.125f * 1.44269504089f;  // scale * log2(e)
  u16* Pw = &sP[w * 16 * 72];

  const int ktmax = 2 * qtile + 1;
  for (int kt = 0; kt <= ktmax; ++kt) {
    async_copy16(Kg + (size_t)(kt * 64) * (2 * CC), sK0w);
    async_copy16(Kg + (size_t)(kt * 64) * (2 * CC) + 32, sK1w);
    async_copy16(Vg + kt * 64, sV0w);
    async_copy16(Vg + kt * 64 + 32, sV1w);
    __syncthreads();

    // Load K and V frags once (reused for both q-frags)
    bf16x8 kf[4][2], vf[4][2];
#pragma unroll
    for (int j = 0; j < 4; ++j) {
      kf[j][0] = ld8(&sK0[(j * 16 + lr) * 32 + qd * 8]);
      kf[j][1] = ld8(&sK1[(j * 16 + lr) * 32 + qd * 8]);
      vf[j][0] = ld8(&sV0[(j * 16 + lr) * 32 + qd * 8]);
      vf[j][1] = ld8(&sV1[(j * 16 + lr) * 32 + qd * 8]);
    }

#pragma unroll
    for (int f = 0; f < 2; ++f) {
      const int basef = q0 + w * 32 + f * 16;       // wave-uniform
      if (kt * 64 > basef + 15) continue;           // fully masked frag: skip
      // S^T = K Q^T: frag j -> (key = kt*64+j*16+qd*4+i, q = lr)
      floatx4 s[4] = {};
#pragma unroll
      for (int j = 0; j < 4; ++j) {
        s[j] = mfma16(kf[j][0], qf[f][0], s[j]);
        s[j] = mfma16(kf[j][1], qf[f][1], s[j]);
      }
      const bool needmask = (kt * 64 + 63 > basef);
      const int myq = basef + lr;
#pragma unroll
      for (int j = 0; j < 4; ++j) {
        float p[4];
#pragma unroll
        for (int i = 0; i < 4; ++i) {
          p[i] = exp2f(s[j][i] * SC);
          if (needmask) {
            const int key = kt * 64 + j * 16 + qd * 4 + i;
            p[i] = (key <= myq) ? p[i] : 0.f;
          }
          lsum[f] += p[i];
        }
        uint2 pk;
        pk.x = __builtin_amdgcn_perm(__float_as_uint(p[1]), __float_as_uint(p[0]), 0x07060302);
        pk.y = __builtin_amdgcn_perm(__float_as_uint(p[3]), __float_as_uint(p[2]), 0x07060302);
        *(uint2*)&Pw[lr * 72 + j * 16 + qd * 4] = pk;
      }
      // P as A-operand (within-wave DS ordering makes this safe w/o barrier)
      const bf16x8 pf0 = ld8(&Pw[lr * 72 + qd * 8]);
      const bf16x8 pf1 = ld8(&Pw[lr * 72 + 32 + qd * 8]);
#pragma unroll
      for (int j = 0; j < 4; ++j) {
        o[f][j] = mfma16(pf0, vf[j][0], o[f][j]);
        o[f][j] = mfma16(pf1, vf[j][1], o[f][j]);
      }
    }
    __syncthreads();
  }

  // l reduction + store per frag
#pragma unroll
  for (int f = 0; f < 2; ++f) {
    float ls = lsum[f];
    ls += __shfl_xor(ls, 16);
    ls += __shfl_xor(ls, 32);      // lane L now holds l for q = L&15
    float linv[4];
#pragma unroll
    for (int i = 0; i < 4; ++i) linv[i] = 1.0f / __shfl(ls, qd * 4 + i);
#pragma unroll
    for (int j = 0; j < 4; ++j)
#pragma unroll
      for (int i = 0; i < 4; ++i) {
        const size_t row = (size_t)b * TT + q0 + w * 32 + f * 16 + qd * 4 + i;
        att[row * CC + h * HD + j * 16 + lr] = f2bf(o[f][j][i] * linv[i]);
      }
  }
}

// ---------------------------------------------------------------------------
// ws layout (bytes):
//   xb   0        .. 16 MiB   bf16 [8192][1024]
//   waT  16 MiB   .. 22 MiB   bf16 [3072][1024]
//   wpT  22 MiB   .. 24 MiB   bf16 [1024][1024]
//   qk   24 MiB   .. 56 MiB   bf16 [8192][2048]   (Q|K)
//   vT   56 MiB   .. 72 MiB   bf16 [4*1024][2048] (V^T per (b,dim))
//   att  72 MiB   .. 88 MiB   bf16 [8192][1024]
// ---------------------------------------------------------------------------
extern "C" void kernel_launch(void* const* d_in, const int* in_sizes, int n_in,
                              void* d_out, int out_size, void* d_ws, size_t ws_size,
                              hipStream_t stream) {
  const float* x      = (const float*)d_in[0];
  const float* w_attn = (const float*)d_in[1];
  const float* w_proj = (const float*)d_in[2];
  const float* b_proj = (const float*)d_in[3];
  float* out = (float*)d_out;

  char* ws = (char*)d_ws;
  u16* xb  = (u16*)(ws + 0);
  u16* waT = (u16*)(ws + 16777216);
  u16* wpT = (u16*)(ws + 23068672);
  u16* qk  = (u16*)(ws + 25165824);
  u16* vT  = (u16*)(ws + 58720256);
  u16* att = (u16*)(ws + 75497472);

  tobf16_kernel<<<8192, 256, 0, stream>>>((const float4*)x, (ushort4*)xb, 2097152);
  transpose_bf16_kernel<<<dim3(48, 16), 256, 0, stream>>>(w_attn, waT, CC, C3);
  transpose_bf16_kernel<<<dim3(16, 16), 256, 0, stream>>>(w_proj, wpT, CC, CC);

  // qkv = x @ w_attn  (M=8192, N=3072, K=1024) -> qk + vT
  gemm_kernel<1><<<dim3(24, 64), 256, 0, stream>>>(xb, waT, nullptr, nullptr, qk, vT,
                                                   BT, C3, CC);
  // attention (128-q blocks, LPT)
  attn_kernel<<<dim3(16, 64), 256, 0, stream>>>(qk, vT, att);

  // out = att @ w_proj + b_proj  (M=8192, N=1024, K=1024), fp32 out
  gemm_kernel<2><<<dim3(8, 64), 256, 0, stream>>>(att, wpT, b_proj, out, nullptr, nullptr,
                                                  BT, CC, CC);
}

// Round 6
// 316.611 us; speedup vs baseline: 1.0542x; 1.0542x over previous
//
#include <hip/hip_runtime.h>

// Problem constants
#define BB 4
#define TT 2048
#define CC 1024
#define C3 3072
#define HH 16
#define HD 64
#define BT 8192   // BB*TT

typedef __bf16 bf16x8 __attribute__((ext_vector_type(8)));
typedef float floatx4 __attribute__((ext_vector_type(4)));
typedef unsigned short u16;

__device__ __forceinline__ u16 f2bf(float f) {
  union { float f; unsigned u; } a; a.f = f;
  return (u16)((a.u + 0x7fffu + ((a.u >> 16) & 1u)) >> 16);  // RNE
}
__device__ __forceinline__ bf16x8 ld8(const u16* p) { return *(const bf16x8*)p; }
__device__ __forceinline__ floatx4 mfma16(bf16x8 a, bf16x8 b, floatx4 c) {
  return __builtin_amdgcn_mfma_f32_16x16x32_bf16(a, b, c, 0, 0, 0);
}
// Async global->LDS, 16B per lane. LDS dest is wave-uniform base + lane*16.
// ONLY used in the strict  async -> __syncthreads -> read  shape (m97-verified).
__device__ __forceinline__ void async_copy16(const u16* g, u16* l) {
  __builtin_amdgcn_global_load_lds(
      (const __attribute__((address_space(1))) unsigned int*)g,
      (__attribute__((address_space(3))) unsigned int*)(unsigned int)(unsigned long long)l,
      16, 0, 0);
}

// ---------------------------------------------------------------------------
// fp32 -> bf16 elementwise (for x)
// ---------------------------------------------------------------------------
__global__ __launch_bounds__(256) void tobf16_kernel(const float4* __restrict__ src,
                                                     ushort4* __restrict__ dst, int n4) {
  int i = blockIdx.x * 256 + threadIdx.x;
  if (i >= n4) return;
  float4 v = src[i];
  ushort4 o; o.x = f2bf(v.x); o.y = f2bf(v.y); o.z = f2bf(v.z); o.w = f2bf(v.w);
  dst[i] = o;
}

// ---------------------------------------------------------------------------
// fp32 [K][N] -> bf16 [N][K] transpose (LDS-tiled, 64x64 tiles)
// ---------------------------------------------------------------------------
__global__ __launch_bounds__(256) void transpose_bf16_kernel(const float* __restrict__ src,
                                                             u16* __restrict__ dst,
                                                             int K, int N) {
  __shared__ float s[64][65];
  const int t = threadIdx.x;
  const int r = t >> 4;           // 0..15
  const int c = (t & 15) * 4;     // 0..60
  const int k0 = blockIdx.y * 64, n0 = blockIdx.x * 64;
#pragma unroll
  for (int i = 0; i < 4; ++i) {
    float4 v = *(const float4*)&src[(size_t)(k0 + r + i * 16) * N + n0 + c];
    s[r + i * 16][c + 0] = v.x; s[r + i * 16][c + 1] = v.y;
    s[r + i * 16][c + 2] = v.z; s[r + i * 16][c + 3] = v.w;
  }
  __syncthreads();
#pragma unroll
  for (int i = 0; i < 4; ++i) {
    const int nn = r + i * 16;
    ushort4 o;
    o.x = f2bf(s[c + 0][nn]); o.y = f2bf(s[c + 1][nn]);
    o.z = f2bf(s[c + 2][nn]); o.w = f2bf(s[c + 3][nn]);
    *(ushort4*)&dst[(size_t)(n0 + nn) * K + k0 + c] = o;
  }
}

// ---------------------------------------------------------------------------
// GEMM (m97 structure): C[M,N] = A[M,K] @ B^T[N,K], 128x128 tile, BK=32.
// MODE 1: qkv epilogue via LDS bounce -> coalesced 128B stores
// MODE 2: fp32 out + bias, direct stores
// ---------------------------------------------------------------------------
template<int MODE>
__global__ __launch_bounds__(256) void gemm_kernel(
    const u16* __restrict__ A, const u16* __restrict__ B,
    const float* __restrict__ bias, float* __restrict__ outf,
    u16* __restrict__ qk, u16* __restrict__ vT,
    int M, int N, int K) {
  __shared__ u16 sA[128 * 32];
  __shared__ u16 sB[128 * 32];
  __shared__ u16 sT[(MODE == 1) ? (4 * 32 * 72) : 4];  // per-wave epilogue bounce

  const int t = threadIdx.x;
  const int w = t >> 6, lane = t & 63, lr = lane & 15, qd = lane >> 4;
  const int wm = w >> 1, wn = w & 1;
  const int m0 = blockIdx.y * 128, n0 = blockIdx.x * 128;

  const int sr = t >> 2;          // staging row 0..63
  const int sc = (t & 3) * 8;     // staging col (u16 units)
  const u16* Ag = A + (size_t)(m0 + sr) * K + sc;
  const u16* Bg = B + (size_t)(n0 + sr) * K + sc;
  u16* sAw = sA + w * 512;
  u16* sBw = sB + w * 512;

  floatx4 acc[4][4] = {};

  for (int k0 = 0; k0 < K; k0 += 32) {
    async_copy16(Ag + k0, sAw);
    async_copy16(Ag + (size_t)64 * K + k0, sAw + 2048);
    async_copy16(Bg + k0, sBw);
    async_copy16(Bg + (size_t)64 * K + k0, sBw + 2048);
    __syncthreads();

    bf16x8 af[4], bf[4];
#pragma unroll
    for (int mj = 0; mj < 4; ++mj) af[mj] = ld8(&sA[(wm * 64 + mj * 16 + lr) * 32 + qd * 8]);
#pragma unroll
    for (int nj = 0; nj < 4; ++nj) bf[nj] = ld8(&sB[(wn * 64 + nj * 16 + lr) * 32 + qd * 8]);
#pragma unroll
    for (int mj = 0; mj < 4; ++mj)
#pragma unroll
      for (int nj = 0; nj < 4; ++nj)
        acc[mj][nj] = mfma16(af[mj], bf[nj], acc[mj][nj]);
    __syncthreads();
  }

  // Epilogue. D layout: col(N)=lane&15, row(M)=(lane>>4)*4+i  [m89/m91]
  const int rowg0 = m0 + wm * 64;
  const int colg0 = n0 + wn * 64;
  if constexpr (MODE == 2) {
#pragma unroll
    for (int nj = 0; nj < 4; ++nj) {
      const int col = colg0 + nj * 16 + lr;
      const float bv = bias[col];
#pragma unroll
      for (int mj = 0; mj < 4; ++mj)
#pragma unroll
        for (int i = 0; i < 4; ++i)
          outf[(size_t)(rowg0 + mj * 16 + qd * 4 + i) * N + col] = acc[mj][nj][i] + bv;
    }
  } else {
    u16* Tw = sT + w * (32 * 72);
    const bool isV = (n0 >= 2 * CC);   // block-uniform
    if (!isV) {
      // Q/K: row-major bounce, then 128B-coalesced row stores
#pragma unroll
      for (int half = 0; half < 2; ++half) {
#pragma unroll
        for (int m2 = 0; m2 < 2; ++m2)
#pragma unroll
          for (int nj = 0; nj < 4; ++nj)
#pragma unroll
            for (int i = 0; i < 4; ++i)
              Tw[(m2 * 16 + qd * 4 + i) * 72 + nj * 16 + lr] =
                  f2bf(acc[half * 2 + m2][nj][i]);
#pragma unroll
        for (int s = 0; s < 4; ++s) {
          const int rl = s * 8 + (lane >> 3);
          const int c0 = (lane & 7) * 8;
          *(bf16x8*)&qk[(size_t)(rowg0 + half * 32 + rl) * (2 * CC) + colg0 + c0] =
              ld8(&Tw[rl * 72 + c0]);
        }
      }
    } else {
      // V: transpose bounce -> vT[b*1024 + dim][t], 128B-coalesced
      const int bI = m0 >> 11;
      const int tbase = (m0 & (TT - 1)) + wm * 64;
      const int dim0 = colg0 - 2 * CC;
#pragma unroll
      for (int half = 0; half < 2; ++half) {
#pragma unroll
        for (int n2 = 0; n2 < 2; ++n2)
#pragma unroll
          for (int mj = 0; mj < 4; ++mj)
#pragma unroll
            for (int i = 0; i < 4; ++i)
              Tw[(n2 * 16 + lr) * 72 + mj * 16 + qd * 4 + i] =
                  f2bf(acc[mj][half * 2 + n2][i]);
#pragma unroll
        for (int s = 0; s < 4; ++s) {
          const int dl = s * 8 + (lane >> 3);
          const int t0 = (lane & 7) * 8;
          *(bf16x8*)&vT[((size_t)(bI << 10) + dim0 + half * 32 + dl) * TT + tbase + t0] =
              ld8(&Tw[dl * 72 + t0]);
        }
      }
    }
  }
}

// ---------------------------------------------------------------------------
// Causal flash attention, fixed-max softmax. R3 tile structure (wave = 16 q,
// block = 64 q, 2048 blocks) + RACE-FREE pipelining: K/V tile kt+1 is
// prefetched into REGISTERS (plain uint4 global loads; HW s_waitcnt tracks
// the dependency) during tile kt's compute, then ds_write_b128 into the
// other LDS buffer. One barrier per tile. No global_load_lds in this kernel.
//   iter kt: ds_write regs->buf[kt&1]; prefetch kt+1; barrier; compute.
//   Disjointness: writes to buf[(kt+1)&1] never touch buf[kt&1] readers, and
//   buf[(kt+1)&1]'s prior readers (iter kt-1) drained before barrier kt.
// qtile = 31-blockIdx.x: longest blocks first (LPT).
// ---------------------------------------------------------------------------
__global__ __launch_bounds__(256, 3) void attn_kernel(const u16* __restrict__ qk,
                                                      const u16* __restrict__ vT,
                                                      u16* __restrict__ att) {
  __shared__ u16 sKV[2][4][64 * 32];  // [buf][K0,K1,V0,V1]
  __shared__ u16 sP[4 * 16 * 72];     // per-wave P [q=16][key=64], stride 72

  const int t = threadIdx.x;
  const int w = t >> 6, lane = t & 63, lr = lane & 15, qd = lane >> 4;
  const int qtile = 31 - blockIdx.x;
  const int bh = blockIdx.y;
  const int b = bh >> 4, h = bh & 15;
  const int q0 = qtile * 64;
  const u16* qbase = qk + (size_t)b * TT * (2 * CC);

  // Q frag (B-operand): q = q0 + w*16 + lr
  const u16* qp = qbase + (size_t)(q0 + w * 16 + lr) * (2 * CC) + h * HD;
  const bf16x8 qf0 = ld8(qp + qd * 8);
  const bf16x8 qf1 = ld8(qp + 32 + qd * 8);

  // Staging: lane (t) covers 16B at row sr=t>>2, col sc=(t&3)*8 of each
  // 64x32 sub-tile -- byte offset t*16, identical to the async layout.
  const int sr = t >> 2, sc = (t & 3) * 8;
  const int so = sr * 32 + sc;    // u16 offset within a sub-tile
  const u16* Kg = qbase + (size_t)sr * (2 * CC) + CC + h * HD + sc;
  const u16* Vg = vT + ((size_t)bh * HD + sr) * TT + sc;

  float lsum = 0.f;                 // per-lane partial: q = lr
  floatx4 o[4] = {};
  const float SC = 0.125f * 1.44269504089f;  // scale * log2(e)
  u16* Pw = &sP[w * 16 * 72];
  const int myq = q0 + w * 16 + lr;

  uint4 rK0, rK1, rV0, rV1;         // prefetch registers
  {
    rK0 = *(const uint4*)(Kg);
    rK1 = *(const uint4*)(Kg + 32);
    rV0 = *(const uint4*)(Vg);
    rV1 = *(const uint4*)(Vg + 32);
  }

  for (int kt = 0; kt <= qtile; ++kt) {
    // publish tile kt (waits on its global loads via register dependency)
    u16* base = &sKV[kt & 1][0][0];
    *(uint4*)&base[so]        = rK0;
    *(uint4*)&base[2048 + so] = rK1;
    *(uint4*)&base[4096 + so] = rV0;
    *(uint4*)&base[6144 + so] = rV1;
    if (kt < qtile) {               // prefetch kt+1 (overlaps compute below)
      const int kn = (kt + 1) * 64;
      rK0 = *(const uint4*)(Kg + (size_t)kn * (2 * CC));
      rK1 = *(const uint4*)(Kg + (size_t)kn * (2 * CC) + 32);
      rV0 = *(const uint4*)(Vg + kn);
      rV1 = *(const uint4*)(Vg + kn + 32);
    }
    __syncthreads();

    const u16* sK0 = &sKV[kt & 1][0][0];
    const u16* sK1 = &sKV[kt & 1][1][0];
    const u16* sV0 = &sKV[kt & 1][2][0];
    const u16* sV1 = &sKV[kt & 1][3][0];

    // S^T = K Q^T: frag j -> element (key = kt*64+j*16+qd*4+i, q = lr)
    floatx4 s[4] = {};
#pragma unroll
    for (int j = 0; j < 4; ++j) {
      bf16x8 kf0 = ld8(&sK0[(j * 16 + lr) * 32 + qd * 8]);
      bf16x8 kf1 = ld8(&sK1[(j * 16 + lr) * 32 + qd * 8]);
      s[j] = mfma16(kf0, qf0, s[j]);
      s[j] = mfma16(kf1, qf1, s[j]);
    }

    const bool diag = (kt == qtile);
#pragma unroll
    for (int j = 0; j < 4; ++j) {
      float p[4];
#pragma unroll
      for (int i = 0; i < 4; ++i) {
        p[i] = exp2f(s[j][i] * SC);
        if (diag) {
          const int key = kt * 64 + j * 16 + qd * 4 + i;
          p[i] = (key <= myq) ? p[i] : 0.f;
        }
        lsum += p[i];
      }
      // pack 4 bf16 (truncate; bias cancels in sum(pV)/sum(p)) -> one b64 write
      uint2 pk;
      pk.x = __builtin_amdgcn_perm(__float_as_uint(p[1]), __float_as_uint(p[0]), 0x07060302);
      pk.y = __builtin_amdgcn_perm(__float_as_uint(p[3]), __float_as_uint(p[2]), 0x07060302);
      *(uint2*)&Pw[lr * 72 + j * 16 + qd * 4] = pk;
    }

    // P as A-operand: row q=lr, keys qd*8.. (within-wave DS ordering: no barrier)
    const bf16x8 pf0 = ld8(&Pw[lr * 72 + qd * 8]);
    const bf16x8 pf1 = ld8(&Pw[lr * 72 + 32 + qd * 8]);

    // O += P V: D row = q (qd*4+i), col = dim (j*16+lr) -- standard layout
#pragma unroll
    for (int j = 0; j < 4; ++j) {
      bf16x8 vf0 = ld8(&sV0[(j * 16 + lr) * 32 + qd * 8]);
      bf16x8 vf1 = ld8(&sV1[(j * 16 + lr) * 32 + qd * 8]);
      o[j] = mfma16(pf0, vf0, o[j]);
      o[j] = mfma16(pf1, vf1, o[j]);
    }
    // no trailing barrier: next iter writes the OTHER buffer (disjoint)
  }

  // l: sum the 4 qd-partials per q (lanes sharing lr), then redistribute to O rows
  lsum += __shfl_xor(lsum, 16);
  lsum += __shfl_xor(lsum, 32);
  float linv[4];
#pragma unroll
  for (int i = 0; i < 4; ++i) linv[i] = 1.0f / __shfl(lsum, qd * 4 + i);

#pragma unroll
  for (int j = 0; j < 4; ++j)
#pragma unroll
    for (int i = 0; i < 4; ++i) {
      const size_t row = (size_t)b * TT + q0 + w * 16 + qd * 4 + i;
      att[row * CC + h * HD + j * 16 + lr] = f2bf(o[j][i] * linv[i]);
    }
}

// ---------------------------------------------------------------------------
// ws layout (bytes):
//   xb   0        .. 16 MiB   bf16 [8192][1024]
//   waT  16 MiB   .. 22 MiB   bf16 [3072][1024]
//   wpT  22 MiB   .. 24 MiB   bf16 [1024][1024]
//   qk   24 MiB   .. 56 MiB   bf16 [8192][2048]   (Q|K)
//   vT   56 MiB   .. 72 MiB   bf16 [4*1024][2048] (V^T per (b,dim))
//   att  72 MiB   .. 88 MiB   bf16 [8192][1024]
// ---------------------------------------------------------------------------
extern "C" void kernel_launch(void* const* d_in, const int* in_sizes, int n_in,
                              void* d_out, int out_size, void* d_ws, size_t ws_size,
                              hipStream_t stream) {
  const float* x      = (const float*)d_in[0];
  const float* w_attn = (const float*)d_in[1];
  const float* w_proj = (const float*)d_in[2];
  const float* b_proj = (const float*)d_in[3];
  float* out = (float*)d_out;

  char* ws = (char*)d_ws;
  u16* xb  = (u16*)(ws + 0);
  u16* waT = (u16*)(ws + 16777216);
  u16* wpT = (u16*)(ws + 23068672);
  u16* qk  = (u16*)(ws + 25165824);
  u16* vT  = (u16*)(ws + 58720256);
  u16* att = (u16*)(ws + 75497472);

  tobf16_kernel<<<8192, 256, 0, stream>>>((const float4*)x, (ushort4*)xb, 2097152);
  transpose_bf16_kernel<<<dim3(48, 16), 256, 0, stream>>>(w_attn, waT, CC, C3);
  transpose_bf16_kernel<<<dim3(16, 16), 256, 0, stream>>>(w_proj, wpT, CC, CC);

  // qkv = x @ w_attn  (M=8192, N=3072, K=1024) -> qk + vT
  gemm_kernel<1><<<dim3(24, 64), 256, 0, stream>>>(xb, waT, nullptr, nullptr, qk, vT,
                                                   BT, C3, CC);
  // attention (64-q blocks, LPT, reg-prefetch double-buffered staging)
  attn_kernel<<<dim3(32, 64), 256, 0, stream>>>(qk, vT, att);

  // out = att @ w_proj + b_proj  (M=8192, N=1024, K=1024), fp32 out
  gemm_kernel<2><<<dim3(8, 64), 256, 0, stream>>>(att, wpT, b_proj, out, nullptr, nullptr,
                                                  BT, CC, CC);
}

// Round 7
// 267.702 us; speedup vs baseline: 1.2468x; 1.1827x over previous
//
#include <hip/hip_runtime.h>

// Problem constants
#define BB 4
#define TT 2048
#define CC 1024
#define C3 3072
#define HH 16
#define HD 64
#define BT 8192   // BB*TT

typedef __bf16 bf16x8 __attribute__((ext_vector_type(8)));
typedef float floatx4 __attribute__((ext_vector_type(4)));
typedef unsigned short u16;

__device__ __forceinline__ u16 f2bf(float f) {
  union { float f; unsigned u; } a; a.f = f;
  return (u16)((a.u + 0x7fffu + ((a.u >> 16) & 1u)) >> 16);  // RNE
}
__device__ __forceinline__ bf16x8 ld8(const u16* p) { return *(const bf16x8*)p; }
__device__ __forceinline__ floatx4 mfma16(bf16x8 a, bf16x8 b, floatx4 c) {
  return __builtin_amdgcn_mfma_f32_16x16x32_bf16(a, b, c, 0, 0, 0);
}
// Async global->LDS, 16B per lane. LDS dest is wave-uniform base + lane*16.
// ONLY used in the strict  async -> __syncthreads -> read  shape (m97-verified).
__device__ __forceinline__ void async_copy16(const u16* g, u16* l) {
  __builtin_amdgcn_global_load_lds(
      (const __attribute__((address_space(1))) unsigned int*)g,
      (__attribute__((address_space(3))) unsigned int*)(unsigned int)(unsigned long long)l,
      16, 0, 0);
}

// ---------------------------------------------------------------------------
// fp32 -> bf16 elementwise (for x)
// ---------------------------------------------------------------------------
__global__ __launch_bounds__(256) void tobf16_kernel(const float4* __restrict__ src,
                                                     ushort4* __restrict__ dst, int n4) {
  int i = blockIdx.x * 256 + threadIdx.x;
  if (i >= n4) return;
  float4 v = src[i];
  ushort4 o; o.x = f2bf(v.x); o.y = f2bf(v.y); o.z = f2bf(v.z); o.w = f2bf(v.w);
  dst[i] = o;
}

// ---------------------------------------------------------------------------
// fp32 [K][N] -> bf16 [N][K] transpose (LDS-tiled, 64x64 tiles)
// ---------------------------------------------------------------------------
__global__ __launch_bounds__(256) void transpose_bf16_kernel(const float* __restrict__ src,
                                                             u16* __restrict__ dst,
                                                             int K, int N) {
  __shared__ float s[64][65];
  const int t = threadIdx.x;
  const int r = t >> 4;           // 0..15
  const int c = (t & 15) * 4;     // 0..60
  const int k0 = blockIdx.y * 64, n0 = blockIdx.x * 64;
#pragma unroll
  for (int i = 0; i < 4; ++i) {
    float4 v = *(const float4*)&src[(size_t)(k0 + r + i * 16) * N + n0 + c];
    s[r + i * 16][c + 0] = v.x; s[r + i * 16][c + 1] = v.y;
    s[r + i * 16][c + 2] = v.z; s[r + i * 16][c + 3] = v.w;
  }
  __syncthreads();
#pragma unroll
  for (int i = 0; i < 4; ++i) {
    const int nn = r + i * 16;
    ushort4 o;
    o.x = f2bf(s[c + 0][nn]); o.y = f2bf(s[c + 1][nn]);
    o.z = f2bf(s[c + 2][nn]); o.w = f2bf(s[c + 3][nn]);
    *(ushort4*)&dst[(size_t)(n0 + nn) * K + k0 + c] = o;
  }
}

// ---------------------------------------------------------------------------
// GEMM (m97 structure): C[M,N] = A[M,K] @ B^T[N,K], 128x128 tile, BK=32.
// MODE 1: qkv epilogue via LDS bounce -> coalesced 128B stores
// MODE 2: fp32 out + bias, direct stores
// ---------------------------------------------------------------------------
template<int MODE>
__global__ __launch_bounds__(256) void gemm_kernel(
    const u16* __restrict__ A, const u16* __restrict__ B,
    const float* __restrict__ bias, float* __restrict__ outf,
    u16* __restrict__ qk, u16* __restrict__ vT,
    int M, int N, int K) {
  __shared__ u16 sA[128 * 32];
  __shared__ u16 sB[128 * 32];
  __shared__ u16 sT[(MODE == 1) ? (4 * 32 * 72) : 4];  // per-wave epilogue bounce

  const int t = threadIdx.x;
  const int w = t >> 6, lane = t & 63, lr = lane & 15, qd = lane >> 4;
  const int wm = w >> 1, wn = w & 1;
  const int m0 = blockIdx.y * 128, n0 = blockIdx.x * 128;

  const int sr = t >> 2;          // staging row 0..63
  const int sc = (t & 3) * 8;     // staging col (u16 units)
  const u16* Ag = A + (size_t)(m0 + sr) * K + sc;
  const u16* Bg = B + (size_t)(n0 + sr) * K + sc;
  u16* sAw = sA + w * 512;
  u16* sBw = sB + w * 512;

  floatx4 acc[4][4] = {};

  for (int k0 = 0; k0 < K; k0 += 32) {
    async_copy16(Ag + k0, sAw);
    async_copy16(Ag + (size_t)64 * K + k0, sAw + 2048);
    async_copy16(Bg + k0, sBw);
    async_copy16(Bg + (size_t)64 * K + k0, sBw + 2048);
    __syncthreads();

    bf16x8 af[4], bf[4];
#pragma unroll
    for (int mj = 0; mj < 4; ++mj) af[mj] = ld8(&sA[(wm * 64 + mj * 16 + lr) * 32 + qd * 8]);
#pragma unroll
    for (int nj = 0; nj < 4; ++nj) bf[nj] = ld8(&sB[(wn * 64 + nj * 16 + lr) * 32 + qd * 8]);
#pragma unroll
    for (int mj = 0; mj < 4; ++mj)
#pragma unroll
      for (int nj = 0; nj < 4; ++nj)
        acc[mj][nj] = mfma16(af[mj], bf[nj], acc[mj][nj]);
    __syncthreads();
  }

  // Epilogue. D layout: col(N)=lane&15, row(M)=(lane>>4)*4+i  [m89/m91]
  const int rowg0 = m0 + wm * 64;
  const int colg0 = n0 + wn * 64;
  if constexpr (MODE == 2) {
#pragma unroll
    for (int nj = 0; nj < 4; ++nj) {
      const int col = colg0 + nj * 16 + lr;
      const float bv = bias[col];
#pragma unroll
      for (int mj = 0; mj < 4; ++mj)
#pragma unroll
        for (int i = 0; i < 4; ++i)
          outf[(size_t)(rowg0 + mj * 16 + qd * 4 + i) * N + col] = acc[mj][nj][i] + bv;
    }
  } else {
    u16* Tw = sT + w * (32 * 72);
    const bool isV = (n0 >= 2 * CC);   // block-uniform
    if (!isV) {
      // Q/K: row-major bounce, then 128B-coalesced row stores
#pragma unroll
      for (int half = 0; half < 2; ++half) {
#pragma unroll
        for (int m2 = 0; m2 < 2; ++m2)
#pragma unroll
          for (int nj = 0; nj < 4; ++nj)
#pragma unroll
            for (int i = 0; i < 4; ++i)
              Tw[(m2 * 16 + qd * 4 + i) * 72 + nj * 16 + lr] =
                  f2bf(acc[half * 2 + m2][nj][i]);
#pragma unroll
        for (int s = 0; s < 4; ++s) {
          const int rl = s * 8 + (lane >> 3);
          const int c0 = (lane & 7) * 8;
          *(bf16x8*)&qk[(size_t)(rowg0 + half * 32 + rl) * (2 * CC) + colg0 + c0] =
              ld8(&Tw[rl * 72 + c0]);
        }
      }
    } else {
      // V: transpose bounce -> vT[b*1024 + dim][t], 128B-coalesced
      const int bI = m0 >> 11;
      const int tbase = (m0 & (TT - 1)) + wm * 64;
      const int dim0 = colg0 - 2 * CC;
#pragma unroll
      for (int half = 0; half < 2; ++half) {
#pragma unroll
        for (int n2 = 0; n2 < 2; ++n2)
#pragma unroll
          for (int mj = 0; mj < 4; ++mj)
#pragma unroll
            for (int i = 0; i < 4; ++i)
              Tw[(n2 * 16 + lr) * 72 + mj * 16 + qd * 4 + i] =
                  f2bf(acc[mj][half * 2 + n2][i]);
#pragma unroll
        for (int s = 0; s < 4; ++s) {
          const int dl = s * 8 + (lane >> 3);
          const int t0 = (lane & 7) * 8;
          *(bf16x8*)&vT[((size_t)(bI << 10) + dim0 + half * 32 + dl) * TT + tbase + t0] =
              ld8(&Tw[dl * 72 + t0]);
        }
      }
    }
  }
}

// ---------------------------------------------------------------------------
// Causal flash attention, fixed-max softmax. Wave = 16 q, block = 64 q.
// Reg-prefetch double buffering, with prefetch issued AFTER the barrier so
// the compiler's vmcnt(0)-before-s_barrier cannot drain it (R6's mistake):
//   iter kt: ds_write regs->buf[kt&1]; barrier; prefetch kt+1; compute kt.
// Loads for kt+1 complete during compute kt; consumed by ds_write at iter
// kt+1 top (HW vmcnt dependency). Disjoint buffers keep it race-free.
// Grid (x=bh, y=qtile): all same-bh blocks land on XCD x%8 -> K/V reuse
// stays in one XCD's L2 (8 bh x 384KB = 3MB < 4MB). qtile = 31-y: LPT.
// ---------------------------------------------------------------------------
__global__ __launch_bounds__(256, 3) void attn_kernel(const u16* __restrict__ qk,
                                                      const u16* __restrict__ vT,
                                                      u16* __restrict__ att) {
  __shared__ u16 sKV[2][4][64 * 32];  // [buf][K0,K1,V0,V1]
  __shared__ u16 sP[4 * 16 * 72];     // per-wave P [q=16][key=64], stride 72

  const int t = threadIdx.x;
  const int w = t >> 6, lane = t & 63, lr = lane & 15, qd = lane >> 4;
  const int qtile = 31 - blockIdx.y;  // LPT: longest first
  const int bh = blockIdx.x;          // x fastest -> XCD = bh % 8 for all qtiles
  const int b = bh >> 4, h = bh & 15;
  const int q0 = qtile * 64;
  const u16* qbase = qk + (size_t)b * TT * (2 * CC);

  // Q frag (B-operand): q = q0 + w*16 + lr
  const u16* qp = qbase + (size_t)(q0 + w * 16 + lr) * (2 * CC) + h * HD;
  const bf16x8 qf0 = ld8(qp + qd * 8);
  const bf16x8 qf1 = ld8(qp + 32 + qd * 8);

  // Staging: lane t covers 16B at row sr=t>>2, col sc=(t&3)*8 of each
  // 64x32 sub-tile (byte offset t*16).
  const int sr = t >> 2, sc = (t & 3) * 8;
  const int so = sr * 32 + sc;    // u16 offset within a sub-tile
  const u16* Kg = qbase + (size_t)sr * (2 * CC) + CC + h * HD + sc;
  const u16* Vg = vT + ((size_t)bh * HD + sr) * TT + sc;

  float lsum = 0.f;                 // per-lane partial: q = lr
  floatx4 o[4] = {};
  const float SC = 0.125f * 1.44269504089f;  // scale * log2(e)
  u16* Pw = &sP[w * 16 * 72];
  const int myq = q0 + w * 16 + lr;

  uint4 rK0, rK1, rV0, rV1;         // prefetch registers (tile 0)
  rK0 = *(const uint4*)(Kg);
  rK1 = *(const uint4*)(Kg + 32);
  rV0 = *(const uint4*)(Vg);
  rV1 = *(const uint4*)(Vg + 32);

  for (int kt = 0; kt <= qtile; ++kt) {
    // publish tile kt (ds_write waits on the global loads via reg dependency)
    u16* base = &sKV[kt & 1][0][0];
    *(uint4*)&base[so]        = rK0;
    *(uint4*)&base[2048 + so] = rK1;
    *(uint4*)&base[4096 + so] = rV0;
    *(uint4*)&base[6144 + so] = rV1;
    __syncthreads();
    if (kt < qtile) {               // prefetch kt+1 AFTER the barrier:
      const int kn = (kt + 1) * 64; // stays in flight through compute below
      rK0 = *(const uint4*)(Kg + (size_t)kn * (2 * CC));
      rK1 = *(const uint4*)(Kg + (size_t)kn * (2 * CC) + 32);
      rV0 = *(const uint4*)(Vg + kn);
      rV1 = *(const uint4*)(Vg + kn + 32);
    }

    const u16* sK0 = &sKV[kt & 1][0][0];
    const u16* sK1 = &sKV[kt & 1][1][0];
    const u16* sV0 = &sKV[kt & 1][2][0];
    const u16* sV1 = &sKV[kt & 1][3][0];

    // S^T = K Q^T: frag j -> element (key = kt*64+j*16+qd*4+i, q = lr)
    floatx4 s[4] = {};
#pragma unroll
    for (int j = 0; j < 4; ++j) {
      bf16x8 kf0 = ld8(&sK0[(j * 16 + lr) * 32 + qd * 8]);
      bf16x8 kf1 = ld8(&sK1[(j * 16 + lr) * 32 + qd * 8]);
      s[j] = mfma16(kf0, qf0, s[j]);
      s[j] = mfma16(kf1, qf1, s[j]);
    }

    const bool diag = (kt == qtile);
#pragma unroll
    for (int j = 0; j < 4; ++j) {
      float p[4];
#pragma unroll
      for (int i = 0; i < 4; ++i) {
        p[i] = exp2f(s[j][i] * SC);
        if (diag) {
          const int key = kt * 64 + j * 16 + qd * 4 + i;
          p[i] = (key <= myq) ? p[i] : 0.f;
        }
        lsum += p[i];
      }
      // pack 4 bf16 (truncate; bias cancels in sum(pV)/sum(p)) -> one b64 write
      uint2 pk;
      pk.x = __builtin_amdgcn_perm(__float_as_uint(p[1]), __float_as_uint(p[0]), 0x07060302);
      pk.y = __builtin_amdgcn_perm(__float_as_uint(p[3]), __float_as_uint(p[2]), 0x07060302);
      *(uint2*)&Pw[lr * 72 + j * 16 + qd * 4] = pk;
    }

    // P as A-operand: row q=lr, keys qd*8.. (within-wave DS ordering: no barrier)
    const bf16x8 pf0 = ld8(&Pw[lr * 72 + qd * 8]);
    const bf16x8 pf1 = ld8(&Pw[lr * 72 + 32 + qd * 8]);

    // O += P V: D row = q (qd*4+i), col = dim (j*16+lr) -- standard layout
#pragma unroll
    for (int j = 0; j < 4; ++j) {
      bf16x8 vf0 = ld8(&sV0[(j * 16 + lr) * 32 + qd * 8]);
      bf16x8 vf1 = ld8(&sV1[(j * 16 + lr) * 32 + qd * 8]);
      o[j] = mfma16(pf0, vf0, o[j]);
      o[j] = mfma16(pf1, vf1, o[j]);
    }
    // no trailing barrier: next iter writes the OTHER buffer (disjoint)
  }

  // l: sum the 4 qd-partials per q (lanes sharing lr), then redistribute to O rows
  lsum += __shfl_xor(lsum, 16);
  lsum += __shfl_xor(lsum, 32);
  float linv[4];
#pragma unroll
  for (int i = 0; i < 4; ++i) linv[i] = 1.0f / __shfl(lsum, qd * 4 + i);

#pragma unroll
  for (int j = 0; j < 4; ++j)
#pragma unroll
    for (int i = 0; i < 4; ++i) {
      const size_t row = (size_t)b * TT + q0 + w * 16 + qd * 4 + i;
      att[row * CC + h * HD + j * 16 + lr] = f2bf(o[j][i] * linv[i]);
    }
}

// ---------------------------------------------------------------------------
// ws layout (bytes):
//   xb   0        .. 16 MiB   bf16 [8192][1024]
//   waT  16 MiB   .. 22 MiB   bf16 [3072][1024]
//   wpT  22 MiB   .. 24 MiB   bf16 [1024][1024]
//   qk   24 MiB   .. 56 MiB   bf16 [8192][2048]   (Q|K)
//   vT   56 MiB   .. 72 MiB   bf16 [4*1024][2048] (V^T per (b,dim))
//   att  72 MiB   .. 88 MiB   bf16 [8192][1024]
// ---------------------------------------------------------------------------
extern "C" void kernel_launch(void* const* d_in, const int* in_sizes, int n_in,
                              void* d_out, int out_size, void* d_ws, size_t ws_size,
                              hipStream_t stream) {
  const float* x      = (const float*)d_in[0];
  const float* w_attn = (const float*)d_in[1];
  const float* w_proj = (const float*)d_in[2];
  const float* b_proj = (const float*)d_in[3];
  float* out = (float*)d_out;

  char* ws = (char*)d_ws;
  u16* xb  = (u16*)(ws + 0);
  u16* waT = (u16*)(ws + 16777216);
  u16* wpT = (u16*)(ws + 23068672);
  u16* qk  = (u16*)(ws + 25165824);
  u16* vT  = (u16*)(ws + 58720256);
  u16* att = (u16*)(ws + 75497472);

  tobf16_kernel<<<8192, 256, 0, stream>>>((const float4*)x, (ushort4*)xb, 2097152);
  transpose_bf16_kernel<<<dim3(48, 16), 256, 0, stream>>>(w_attn, waT, CC, C3);
  transpose_bf16_kernel<<<dim3(16, 16), 256, 0, stream>>>(w_proj, wpT, CC, CC);

  // qkv = x @ w_attn  (M=8192, N=3072, K=1024) -> qk + vT
  gemm_kernel<1><<<dim3(24, 64), 256, 0, stream>>>(xb, waT, nullptr, nullptr, qk, vT,
                                                   BT, C3, CC);
  // attention: grid (bh, qtile) -> same-bh blocks share an XCD; LPT in y
  attn_kernel<<<dim3(64, 32), 256, 0, stream>>>(qk, vT, att);

  // out = att @ w_proj + b_proj  (M=8192, N=1024, K=1024), fp32 out
  gemm_kernel<2><<<dim3(8, 64), 256, 0, stream>>>(att, wpT, b_proj, out, nullptr, nullptr,
                                                  BT, CC, CC);
}

// Round 8
// 259.418 us; speedup vs baseline: 1.2866x; 1.0319x over previous
//
#include <hip/hip_runtime.h>

// Problem constants
#define BB 4
#define TT 2048
#define CC 1024
#define C3 3072
#define HH 16
#define HD 64
#define BT 8192   // BB*TT

typedef __bf16 bf16x8 __attribute__((ext_vector_type(8)));
typedef float floatx4 __attribute__((ext_vector_type(4)));
typedef unsigned short u16;

__device__ __forceinline__ u16 f2bf(float f) {
  union { float f; unsigned u; } a; a.f = f;
  return (u16)((a.u + 0x7fffu + ((a.u >> 16) & 1u)) >> 16);  // RNE
}
__device__ __forceinline__ bf16x8 ld8(const u16* p) { return *(const bf16x8*)p; }
__device__ __forceinline__ floatx4 mfma16(bf16x8 a, bf16x8 b, floatx4 c) {
  return __builtin_amdgcn_mfma_f32_16x16x32_bf16(a, b, c, 0, 0, 0);
}

// ---------------------------------------------------------------------------
// fp32 -> bf16 elementwise (for x)
// ---------------------------------------------------------------------------
__global__ __launch_bounds__(256) void tobf16_kernel(const float4* __restrict__ src,
                                                     ushort4* __restrict__ dst, int n4) {
  int i = blockIdx.x * 256 + threadIdx.x;
  if (i >= n4) return;
  float4 v = src[i];
  ushort4 o; o.x = f2bf(v.x); o.y = f2bf(v.y); o.z = f2bf(v.z); o.w = f2bf(v.w);
  dst[i] = o;
}

// ---------------------------------------------------------------------------
// fp32 [K][N] -> bf16 [N][K] transpose (LDS-tiled, 64x64 tiles)
// ---------------------------------------------------------------------------
__global__ __launch_bounds__(256) void transpose_bf16_kernel(const float* __restrict__ src,
                                                             u16* __restrict__ dst,
                                                             int K, int N) {
  __shared__ float s[64][65];
  const int t = threadIdx.x;
  const int r = t >> 4;           // 0..15
  const int c = (t & 15) * 4;     // 0..60
  const int k0 = blockIdx.y * 64, n0 = blockIdx.x * 64;
#pragma unroll
  for (int i = 0; i < 4; ++i) {
    float4 v = *(const float4*)&src[(size_t)(k0 + r + i * 16) * N + n0 + c];
    s[r + i * 16][c + 0] = v.x; s[r + i * 16][c + 1] = v.y;
    s[r + i * 16][c + 2] = v.z; s[r + i * 16][c + 3] = v.w;
  }
  __syncthreads();
#pragma unroll
  for (int i = 0; i < 4; ++i) {
    const int nn = r + i * 16;
    ushort4 o;
    o.x = f2bf(s[c + 0][nn]); o.y = f2bf(s[c + 1][nn]);
    o.z = f2bf(s[c + 2][nn]); o.w = f2bf(s[c + 3][nn]);
    *(ushort4*)&dst[(size_t)(n0 + nn) * K + k0 + c] = o;
  }
}

// ---------------------------------------------------------------------------
// GEMM: C[M,N] = A[M,K] @ B^T[N,K], 128x128 tile, BK=32, 256 thr = 4 waves.
// R7-attn-style pipeline (replaces m97 global_load_lds 2-barrier shape):
//   iter k: ds_write regs->buf[p]; barrier; prefetch k+32 (plain uint4 loads,
//   in flight through compute); compute buf[p].  One barrier per K-iter;
//   no vmcnt(0)-before-barrier drain (loads consumed by ds_write via reg dep).
// Disjointness: buf[p^1]'s last readers (iter k-32) drained their ds_reads
// before barrier@k, and writes to buf[p^1] occur after barrier@k.
// MODE 1: qkv epilogue via LDS bounce (aliased onto staging smem after a
//         barrier) -> coalesced 128B stores (Q,K row-major; V transposed)
// MODE 2: fp32 out + bias, direct stores
// ---------------------------------------------------------------------------
template<int MODE>
__global__ __launch_bounds__(256) void gemm_kernel(
    const u16* __restrict__ A, const u16* __restrict__ B,
    const float* __restrict__ bias, float* __restrict__ outf,
    u16* __restrict__ qk, u16* __restrict__ vT,
    int M, int N, int K) {
  __shared__ u16 smem[2][2][4096];   // [buf][A|B][128x32]  = 32 KB

  const int t = threadIdx.x;
  const int w = t >> 6, lane = t & 63, lr = lane & 15, qd = lane >> 4;
  const int wm = w >> 1, wn = w & 1;
  const int m0 = blockIdx.y * 128, n0 = blockIdx.x * 128;

  // Staging: lane t covers 16B at row sr (0..63) col sc of each 64x32
  // half-tile; half 2 is rows 64..127. u16 offset so = t*8.
  const int sr = t >> 2;
  const int sc = (t & 3) * 8;
  const int so = sr * 32 + sc;
  const u16* Ag = A + (size_t)(m0 + sr) * K + sc;
  const u16* Bg = B + (size_t)(n0 + sr) * K + sc;

  floatx4 acc[4][4] = {};

  uint4 rA0, rA1, rB0, rB1;          // prefetch registers (tile k0=0)
  rA0 = *(const uint4*)(Ag);
  rA1 = *(const uint4*)(Ag + (size_t)64 * K);
  rB0 = *(const uint4*)(Bg);
  rB1 = *(const uint4*)(Bg + (size_t)64 * K);

  for (int k0 = 0; k0 < K; k0 += 32) {
    const int p = (k0 >> 5) & 1;
    u16* sA = &smem[p][0][0];
    u16* sB = &smem[p][1][0];
    *(uint4*)&sA[so]        = rA0;
    *(uint4*)&sA[2048 + so] = rA1;
    *(uint4*)&sB[so]        = rB0;
    *(uint4*)&sB[2048 + so] = rB1;
    __syncthreads();
    if (k0 + 32 < K) {               // prefetch AFTER the barrier
      rA0 = *(const uint4*)(Ag + k0 + 32);
      rA1 = *(const uint4*)(Ag + (size_t)64 * K + k0 + 32);
      rB0 = *(const uint4*)(Bg + k0 + 32);
      rB1 = *(const uint4*)(Bg + (size_t)64 * K + k0 + 32);
    }

    bf16x8 af[4], bf[4];
#pragma unroll
    for (int mj = 0; mj < 4; ++mj) af[mj] = ld8(&sA[(wm * 64 + mj * 16 + lr) * 32 + qd * 8]);
#pragma unroll
    for (int nj = 0; nj < 4; ++nj) bf[nj] = ld8(&sB[(wn * 64 + nj * 16 + lr) * 32 + qd * 8]);
#pragma unroll
    for (int mj = 0; mj < 4; ++mj)
#pragma unroll
      for (int nj = 0; nj < 4; ++nj)
        acc[mj][nj] = mfma16(af[mj], bf[nj], acc[mj][nj]);
    // no trailing barrier: next iter writes the OTHER buffer (disjoint)
  }

  // Epilogue. D layout: col(N)=lane&15, row(M)=(lane>>4)*4+i  [m89/m91]
  const int rowg0 = m0 + wm * 64;
  const int colg0 = n0 + wn * 64;
  if constexpr (MODE == 2) {
#pragma unroll
    for (int nj = 0; nj < 4; ++nj) {
      const int col = colg0 + nj * 16 + lr;
      const float bv = bias[col];
#pragma unroll
      for (int mj = 0; mj < 4; ++mj)
#pragma unroll
        for (int i = 0; i < 4; ++i)
          outf[(size_t)(rowg0 + mj * 16 + qd * 4 + i) * N + col] = acc[mj][nj][i] + bv;
    }
  } else {
    __syncthreads();   // all waves done reading staging smem; reuse as bounce
    u16* Tw = &smem[0][0][0] + w * (32 * 72);
    const bool isV = (n0 >= 2 * CC);   // block-uniform
    if (!isV) {
      // Q/K: row-major bounce, then 128B-coalesced row stores
#pragma unroll
      for (int half = 0; half < 2; ++half) {
#pragma unroll
        for (int m2 = 0; m2 < 2; ++m2)
#pragma unroll
          for (int nj = 0; nj < 4; ++nj)
#pragma unroll
            for (int i = 0; i < 4; ++i)
              Tw[(m2 * 16 + qd * 4 + i) * 72 + nj * 16 + lr] =
                  f2bf(acc[half * 2 + m2][nj][i]);
#pragma unroll
        for (int s = 0; s < 4; ++s) {
          const int rl = s * 8 + (lane >> 3);
          const int c0 = (lane & 7) * 8;
          *(bf16x8*)&qk[(size_t)(rowg0 + half * 32 + rl) * (2 * CC) + colg0 + c0] =
              ld8(&Tw[rl * 72 + c0]);
        }
      }
    } else {
      // V: transpose bounce -> vT[b*1024 + dim][t], 128B-coalesced
      const int bI = m0 >> 11;
      const int tbase = (m0 & (TT - 1)) + wm * 64;
      const int dim0 = colg0 - 2 * CC;
#pragma unroll
      for (int half = 0; half < 2; ++half) {
#pragma unroll
        for (int n2 = 0; n2 < 2; ++n2)
#pragma unroll
          for (int mj = 0; mj < 4; ++mj)
#pragma unroll
            for (int i = 0; i < 4; ++i)
              Tw[(n2 * 16 + lr) * 72 + mj * 16 + qd * 4 + i] =
                  f2bf(acc[mj][half * 2 + n2][i]);
#pragma unroll
        for (int s = 0; s < 4; ++s) {
          const int dl = s * 8 + (lane >> 3);
          const int t0 = (lane & 7) * 8;
          *(bf16x8*)&vT[((size_t)(bI << 10) + dim0 + half * 32 + dl) * TT + tbase + t0] =
              ld8(&Tw[dl * 72 + t0]);
        }
      }
    }
  }
}

// ---------------------------------------------------------------------------
// Causal flash attention, fixed-max softmax. Wave = 16 q, block = 64 q.
// Reg-prefetch double buffering, prefetch issued AFTER the barrier:
//   iter kt: ds_write regs->buf[kt&1]; barrier; prefetch kt+1; compute kt.
// Grid (x=bh, y=qtile): same-bh blocks share an XCD (K/V stay in its L2).
// qtile = 31-y: LPT. (R7: 133 -> <80 us)
// ---------------------------------------------------------------------------
__global__ __launch_bounds__(256, 3) void attn_kernel(const u16* __restrict__ qk,
                                                      const u16* __restrict__ vT,
                                                      u16* __restrict__ att) {
  __shared__ u16 sKV[2][4][64 * 32];  // [buf][K0,K1,V0,V1]
  __shared__ u16 sP[4 * 16 * 72];     // per-wave P [q=16][key=64], stride 72

  const int t = threadIdx.x;
  const int w = t >> 6, lane = t & 63, lr = lane & 15, qd = lane >> 4;
  const int qtile = 31 - blockIdx.y;  // LPT: longest first
  const int bh = blockIdx.x;          // x fastest -> XCD = bh % 8 for all qtiles
  const int b = bh >> 4, h = bh & 15;
  const int q0 = qtile * 64;
  const u16* qbase = qk + (size_t)b * TT * (2 * CC);

  // Q frag (B-operand): q = q0 + w*16 + lr
  const u16* qp = qbase + (size_t)(q0 + w * 16 + lr) * (2 * CC) + h * HD;
  const bf16x8 qf0 = ld8(qp + qd * 8);
  const bf16x8 qf1 = ld8(qp + 32 + qd * 8);

  const int sr = t >> 2, sc = (t & 3) * 8;
  const int so = sr * 32 + sc;    // u16 offset within a sub-tile
  const u16* Kg = qbase + (size_t)sr * (2 * CC) + CC + h * HD + sc;
  const u16* Vg = vT + ((size_t)bh * HD + sr) * TT + sc;

  float lsum = 0.f;                 // per-lane partial: q = lr
  floatx4 o[4] = {};
  const float SC = 0.125f * 1.44269504089f;  // scale * log2(e)
  u16* Pw = &sP[w * 16 * 72];
  const int myq = q0 + w * 16 + lr;

  uint4 rK0, rK1, rV0, rV1;         // prefetch registers (tile 0)
  rK0 = *(const uint4*)(Kg);
  rK1 = *(const uint4*)(Kg + 32);
  rV0 = *(const uint4*)(Vg);
  rV1 = *(const uint4*)(Vg + 32);

  for (int kt = 0; kt <= qtile; ++kt) {
    u16* base = &sKV[kt & 1][0][0];
    *(uint4*)&base[so]        = rK0;
    *(uint4*)&base[2048 + so] = rK1;
    *(uint4*)&base[4096 + so] = rV0;
    *(uint4*)&base[6144 + so] = rV1;
    __syncthreads();
    if (kt < qtile) {               // prefetch kt+1 AFTER the barrier
      const int kn = (kt + 1) * 64;
      rK0 = *(const uint4*)(Kg + (size_t)kn * (2 * CC));
      rK1 = *(const uint4*)(Kg + (size_t)kn * (2 * CC) + 32);
      rV0 = *(const uint4*)(Vg + kn);
      rV1 = *(const uint4*)(Vg + kn + 32);
    }

    const u16* sK0 = &sKV[kt & 1][0][0];
    const u16* sK1 = &sKV[kt & 1][1][0];
    const u16* sV0 = &sKV[kt & 1][2][0];
    const u16* sV1 = &sKV[kt & 1][3][0];

    // S^T = K Q^T: frag j -> element (key = kt*64+j*16+qd*4+i, q = lr)
    floatx4 s[4] = {};
#pragma unroll
    for (int j = 0; j < 4; ++j) {
      bf16x8 kf0 = ld8(&sK0[(j * 16 + lr) * 32 + qd * 8]);
      bf16x8 kf1 = ld8(&sK1[(j * 16 + lr) * 32 + qd * 8]);
      s[j] = mfma16(kf0, qf0, s[j]);
      s[j] = mfma16(kf1, qf1, s[j]);
    }

    const bool diag = (kt == qtile);
#pragma unroll
    for (int j = 0; j < 4; ++j) {
      float p[4];
#pragma unroll
      for (int i = 0; i < 4; ++i) {
        p[i] = exp2f(s[j][i] * SC);
        if (diag) {
          const int key = kt * 64 + j * 16 + qd * 4 + i;
          p[i] = (key <= myq) ? p[i] : 0.f;
        }
        lsum += p[i];
      }
      // pack 4 bf16 (truncate; bias cancels in sum(pV)/sum(p)) -> one b64 write
      uint2 pk;
      pk.x = __builtin_amdgcn_perm(__float_as_uint(p[1]), __float_as_uint(p[0]), 0x07060302);
      pk.y = __builtin_amdgcn_perm(__float_as_uint(p[3]), __float_as_uint(p[2]), 0x07060302);
      *(uint2*)&Pw[lr * 72 + j * 16 + qd * 4] = pk;
    }

    // P as A-operand: row q=lr, keys qd*8.. (within-wave DS ordering: no barrier)
    const bf16x8 pf0 = ld8(&Pw[lr * 72 + qd * 8]);
    const bf16x8 pf1 = ld8(&Pw[lr * 72 + 32 + qd * 8]);

    // O += P V: D row = q (qd*4+i), col = dim (j*16+lr) -- standard layout
#pragma unroll
    for (int j = 0; j < 4; ++j) {
      bf16x8 vf0 = ld8(&sV0[(j * 16 + lr) * 32 + qd * 8]);
      bf16x8 vf1 = ld8(&sV1[(j * 16 + lr) * 32 + qd * 8]);
      o[j] = mfma16(pf0, vf0, o[j]);
      o[j] = mfma16(pf1, vf1, o[j]);
    }
    // no trailing barrier: next iter writes the OTHER buffer (disjoint)
  }

  // l: sum the 4 qd-partials per q (lanes sharing lr), then redistribute to O rows
  lsum += __shfl_xor(lsum, 16);
  lsum += __shfl_xor(lsum, 32);
  float linv[4];
#pragma unroll
  for (int i = 0; i < 4; ++i) linv[i] = 1.0f / __shfl(lsum, qd * 4 + i);

#pragma unroll
  for (int j = 0; j < 4; ++j)
#pragma unroll
    for (int i = 0; i < 4; ++i) {
      const size_t row = (size_t)b * TT + q0 + w * 16 + qd * 4 + i;
      att[row * CC + h * HD + j * 16 + lr] = f2bf(o[j][i] * linv[i]);
    }
}

// ---------------------------------------------------------------------------
// ws layout (bytes):
//   xb   0        .. 16 MiB   bf16 [8192][1024]
//   waT  16 MiB   .. 22 MiB   bf16 [3072][1024]
//   wpT  22 MiB   .. 24 MiB   bf16 [1024][1024]
//   qk   24 MiB   .. 56 MiB   bf16 [8192][2048]   (Q|K)
//   vT   56 MiB   .. 72 MiB   bf16 [4*1024][2048] (V^T per (b,dim))
//   att  72 MiB   .. 88 MiB   bf16 [8192][1024]
// ---------------------------------------------------------------------------
extern "C" void kernel_launch(void* const* d_in, const int* in_sizes, int n_in,
                              void* d_out, int out_size, void* d_ws, size_t ws_size,
                              hipStream_t stream) {
  const float* x      = (const float*)d_in[0];
  const float* w_attn = (const float*)d_in[1];
  const float* w_proj = (const float*)d_in[2];
  const float* b_proj = (const float*)d_in[3];
  float* out = (float*)d_out;

  char* ws = (char*)d_ws;
  u16* xb  = (u16*)(ws + 0);
  u16* waT = (u16*)(ws + 16777216);
  u16* wpT = (u16*)(ws + 23068672);
  u16* qk  = (u16*)(ws + 25165824);
  u16* vT  = (u16*)(ws + 58720256);
  u16* att = (u16*)(ws + 75497472);

  tobf16_kernel<<<8192, 256, 0, stream>>>((const float4*)x, (ushort4*)xb, 2097152);
  transpose_bf16_kernel<<<dim3(48, 16), 256, 0, stream>>>(w_attn, waT, CC, C3);
  transpose_bf16_kernel<<<dim3(16, 16), 256, 0, stream>>>(w_proj, wpT, CC, CC);

  // qkv = x @ w_attn  (M=8192, N=3072, K=1024) -> qk + vT
  gemm_kernel<1><<<dim3(24, 64), 256, 0, stream>>>(xb, waT, nullptr, nullptr, qk, vT,
                                                   BT, C3, CC);
  // attention: grid (bh, qtile) -> same-bh blocks share an XCD; LPT in y
  attn_kernel<<<dim3(64, 32), 256, 0, stream>>>(qk, vT, att);

  // out = att @ w_proj + b_proj  (M=8192, N=1024, K=1024), fp32 out
  gemm_kernel<2><<<dim3(8, 64), 256, 0, stream>>>(att, wpT, b_proj, out, nullptr, nullptr,
                                                  BT, CC, CC);
}